// Round 8
// baseline (607.886 us; speedup 1.0000x reference)
//
#include <hip/hip_runtime.h>

// B=65536, C=2, P=41, L=4: loss = mean( ce*w + 0.001*conn )
//   ce   = relu(l_other - l_target) + log(1+exp(-|l1-l0|))
//   w    = 1 + |t[p]-t[p-1]| + |t[p+1]-t[p]| + 0.5(|t[p]-t[p-2]| + |t[p+2]-t[p]|)
//   conn = (pred[p] != pred[p-1]), p>=1; pred = (l1 > l0)
//
// Round 8: round-7 branch-free body + fused last-block reduction (saves the
// second dispatch). Cross-block comms via device-scope atomics only (safe
// across non-coherent per-XCD L2s): 256 spread accumulator slots + counter.
constexpr int B    = 65536;
constexpr int P    = 41;
constexpr int NTH  = B * P;          // 2,686,976 = 10,496 * 256 exactly (no tail)
constexpr int NBLK = NTH / 256;      // 10,496
constexpr float INV_N = 1.0f / (float)(B * P * 4);
constexpr float CW    = 0.001f;

__device__ __forceinline__ float comp1(float l0, float l1, float q0, float q1,
                                       int tx, int am1, int ap1, int am2, int ap2)
{
    float d  = l1 - l0;
    float g  = __logf(1.0f + __expf(-fabsf(d)));
    float ft = (float)tx;
    float sd = d * fmaf(-2.0f, ft, 1.0f);        // l_other - l_target
    float ce = fmaxf(sd, 0.0f) + g;

    int   x1 = (tx ^ am1) + (tx ^ ap1);          // 0..2
    int   x2 = (tx ^ am2) + (tx ^ ap2);          // 0..2
    float w  = fmaf(0.5f, (float)x2, 1.0f + (float)x1);

    float dm   = q1 - q0;                        // prev-p logit diff (self at p=0)
    float conn = ((d > 0.0f) != (dm > 0.0f)) ? CW : 0.0f;
    return fmaf(ce, w, conn);
}

__global__ __launch_bounds__(256)
void lace_kernel(const float4* __restrict__ lg4,
                 const int4*   __restrict__ tg4,
                 float*        __restrict__ acc,      // [256], zeroed
                 unsigned int* __restrict__ counter,  // [1], zeroed
                 float*        __restrict__ out)
{
    const int t = blockIdx.x * 256 + threadIdx.x;   // (b,p) pair id, no tail
    const int b = t / P;                             // magic-mul
    const int p = t - b * P;

    // clamped-to-self neighbor positions (reproduce bounds guards exactly)
    const int pm1 = (p >= 1) ? p - 1 : p;
    const int pp1 = (p <= P - 2) ? p + 1 : p;
    const int pm2 = (p >= 2) ? p - 2 : p;
    const int pp2 = (p <= P - 3) ? p + 2 : p;

    const int f4 = b * 82 + p;                       // float4 idx of logits[b,0,p,:]
    const int fm = b * 82 + pm1;
    const int tb = t - p;                            // b*41

    // ---- 9 unconditional, independent loads ----
    float4 a0 = lg4[f4];
    float4 a1 = lg4[f4 + 41];
    float4 q0 = lg4[fm];
    float4 q1 = lg4[fm + 41];
    int4   tc = tg4[t];
    int4   nA = tg4[tb + pm1];
    int4   nB = tg4[tb + pp1];
    int4   nC = tg4[tb + pm2];
    int4   nD = tg4[tb + pp2];

    float sum = comp1(a0.x, a1.x, q0.x, q1.x, tc.x, nA.x, nB.x, nC.x, nD.x)
              + comp1(a0.y, a1.y, q0.y, q1.y, tc.y, nA.y, nB.y, nC.y, nD.y)
              + comp1(a0.z, a1.z, q0.z, q1.z, tc.z, nA.z, nB.z, nC.z, nD.z)
              + comp1(a0.w, a1.w, q0.w, q1.w, tc.w, nA.w, nB.w, nC.w, nD.w);

    // ---- block reduction ----
    #pragma unroll
    for (int off = 32; off > 0; off >>= 1)
        sum += __shfl_down(sum, off, 64);

    __shared__ float wsum[4];
    __shared__ bool  isLast;
    const int lane = threadIdx.x & 63;
    const int wid  = threadIdx.x >> 6;
    if (lane == 0) wsum[wid] = sum;
    __syncthreads();

    if (threadIdx.x == 0) {
        float bs = wsum[0] + wsum[1] + wsum[2] + wsum[3];
        atomicAdd(&acc[blockIdx.x & 255], bs);      // spread over 64 cache lines
        __threadfence();                             // acc-add visible before count
        unsigned prev = atomicAdd(counter, 1u);
        isLast = (prev == (unsigned)(NBLK - 1));
    }
    __syncthreads();

    // ---- last block folds the 256 slots ----
    if (isLast) {
        __threadfence();
        float v = atomicAdd(&acc[threadIdx.x], 0.0f);   // coherent RMW read
        #pragma unroll
        for (int off = 32; off > 0; off >>= 1)
            v += __shfl_down(v, off, 64);
        if (lane == 0) wsum[wid] = v;
        __syncthreads();
        if (threadIdx.x == 0)
            out[0] = (wsum[0] + wsum[1] + wsum[2] + wsum[3]) * INV_N;
    }
}

extern "C" void kernel_launch(void* const* d_in, const int* in_sizes, int n_in,
                              void* d_out, int out_size, void* d_ws, size_t ws_size,
                              hipStream_t stream) {
    const float4* lg4 = (const float4*)d_in[0];
    const int4*   tg4 = (const int4*)d_in[1];
    float* out = (float*)d_out;

    float*        acc     = (float*)d_ws;              // 256 floats
    unsigned int* counter = (unsigned int*)((char*)d_ws + 1024);

    // zero accumulators + counter (ws is re-poisoned to 0xAA before every call)
    hipMemsetAsync(d_ws, 0, 1028, stream);

    lace_kernel<<<NBLK, 256, 0, stream>>>(lg4, tg4, acc, counter, out);
}

// Round 9
// 156.951 us; speedup vs baseline: 3.8731x; 3.8731x over previous
//
#include <hip/hip_runtime.h>

// B=65536, C=2, P=41, L=4: loss = mean( ce*w + 0.001*conn )
//   ce   = relu(l_other - l_target) + log(1+exp(-|l1-l0|))
//   w    = 1 + |t[p]-t[p-1]| + |t[p+1]-t[p]| + 0.5(|t[p]-t[p-2]| + |t[p+2]-t[p]|), bounds-guarded
//   conn = (pred[p] != pred[p-1]), p>=1; pred = (l1 > l0)
//
// Round 9 = round 7 revert (best measured: 155.8 us total).
// Branch-free: boundary guards via clamp-to-self neighbor indices (t^t=0
// reproduces the guard; self-pred makes conn=0 at p=0). All 9 loads
// unconditional & independent -> max MLP, zero exec-mask churn.
// Round 8's fused last-block reduction REGRESSED 4x (per-block
// __threadfence + counter atomic serialized ~44 us/generation) - do not refuse.
constexpr int B    = 65536;
constexpr int P    = 41;
constexpr int NTH  = B * P;          // 2,686,976 = 10,496 * 256 exactly (no tail)
constexpr int NBLK = NTH / 256;      // 10,496
constexpr float INV_N = 1.0f / (float)(B * P * 4);
constexpr float CW    = 0.001f;

__device__ __forceinline__ float comp1(float l0, float l1, float q0, float q1,
                                       int tx, int am1, int ap1, int am2, int ap2)
{
    float d  = l1 - l0;
    float g  = __logf(1.0f + __expf(-fabsf(d)));
    float ft = (float)tx;
    float sd = d * fmaf(-2.0f, ft, 1.0f);        // l_other - l_target
    float ce = fmaxf(sd, 0.0f) + g;

    int   x1 = (tx ^ am1) + (tx ^ ap1);          // 0..2
    int   x2 = (tx ^ am2) + (tx ^ ap2);          // 0..2
    float w  = fmaf(0.5f, (float)x2, 1.0f + (float)x1);

    float dm   = q1 - q0;                        // prev-p logit diff (self at p=0)
    float conn = ((d > 0.0f) != (dm > 0.0f)) ? CW : 0.0f;
    return fmaf(ce, w, conn);
}

__global__ __launch_bounds__(256)
void lace_partial_kernel(const float4* __restrict__ lg4,
                         const int4*   __restrict__ tg4,
                         float*        __restrict__ partial)
{
    const int t = blockIdx.x * 256 + threadIdx.x;   // (b,p) pair id, no tail
    const int b = t / P;                             // magic-mul
    const int p = t - b * P;

    // clamped-to-self neighbor positions (reproduce bounds guards exactly)
    const int pm1 = (p >= 1) ? p - 1 : p;            // max(p-1,0)
    const int pp1 = (p <= P - 2) ? p + 1 : p;        // min(p+1,40)
    const int pm2 = (p >= 2) ? p - 2 : p;            // p=1 -> self (guard), not 0
    const int pp2 = (p <= P - 3) ? p + 2 : p;

    const int f4 = b * 82 + p;                       // float4 idx of logits[b,0,p,:]
    const int fm = b * 82 + pm1;
    const int tb = t - p;                            // b*41

    // ---- 9 unconditional, independent loads ----
    float4 a0 = lg4[f4];
    float4 a1 = lg4[f4 + 41];
    float4 q0 = lg4[fm];
    float4 q1 = lg4[fm + 41];
    int4   tc = tg4[t];
    int4   nA = tg4[tb + pm1];
    int4   nB = tg4[tb + pp1];
    int4   nC = tg4[tb + pm2];
    int4   nD = tg4[tb + pp2];

    float sum = comp1(a0.x, a1.x, q0.x, q1.x, tc.x, nA.x, nB.x, nC.x, nD.x)
              + comp1(a0.y, a1.y, q0.y, q1.y, tc.y, nA.y, nB.y, nC.y, nD.y)
              + comp1(a0.z, a1.z, q0.z, q1.z, tc.z, nA.z, nB.z, nC.z, nD.z)
              + comp1(a0.w, a1.w, q0.w, q1.w, tc.w, nA.w, nB.w, nC.w, nD.w);

    // ---- block reduction -> one plain store per block (no atomics) ----
    #pragma unroll
    for (int off = 32; off > 0; off >>= 1)
        sum += __shfl_down(sum, off, 64);

    __shared__ float wsum[4];
    const int lane = threadIdx.x & 63;
    const int wid  = threadIdx.x >> 6;
    if (lane == 0) wsum[wid] = sum;
    __syncthreads();
    if (threadIdx.x == 0)
        partial[blockIdx.x] = wsum[0] + wsum[1] + wsum[2] + wsum[3];
}

__global__ __launch_bounds__(1024)
void lace_reduce_kernel(const float* __restrict__ partial,
                        float*       __restrict__ out)
{
    float s = 0.0f;
    for (int i = threadIdx.x; i < NBLK; i += 1024)
        s += partial[i];

    #pragma unroll
    for (int off = 32; off > 0; off >>= 1)
        s += __shfl_down(s, off, 64);

    __shared__ float wsum[16];
    const int lane = threadIdx.x & 63;
    const int wid  = threadIdx.x >> 6;
    if (lane == 0) wsum[wid] = s;
    __syncthreads();
    if (threadIdx.x == 0) {
        float total = 0.0f;
        #pragma unroll
        for (int i = 0; i < 16; ++i) total += wsum[i];
        out[0] = total * INV_N;
    }
}

extern "C" void kernel_launch(void* const* d_in, const int* in_sizes, int n_in,
                              void* d_out, int out_size, void* d_ws, size_t ws_size,
                              hipStream_t stream) {
    const float4* lg4 = (const float4*)d_in[0];
    const int4*   tg4 = (const int4*)d_in[1];
    float* out     = (float*)d_out;
    float* partial = (float*)d_ws;   // 10,496 floats

    lace_partial_kernel<<<NBLK, 256, 0, stream>>>(lg4, tg4, partial);
    lace_reduce_kernel<<<1, 1024, 0, stream>>>(partial, out);
}